// Round 5
// baseline (31.893 us; speedup 1.0000x reference)
//
#include <hip/hip_runtime.h>
#include <math.h>

#define N_ROWS 4096
#define D_DIM  128
#define K_CLS  512
#define EPS    1e-6f
#define NBLK   (N_ROWS / 16)   // 256 blocks, one per CU

typedef __attribute__((ext_vector_type(8))) short short8v;
typedef __attribute__((ext_vector_type(4))) float f32x4;

__device__ __forceinline__ unsigned short f2bf(float f) {
    unsigned int u = __float_as_uint(f);
    u += 0x7FFF + ((u >> 16) & 1);   // round-to-nearest-even
    return (unsigned short)(u >> 16);
}

// One fused kernel: block = 16 rows x 512 cols, 512 threads (8 waves).
// Wave w owns cols 64w..64w+63. B-fragments loaded straight from global w
// (L2-hot) with on-the-fly bf16 convert; c[k] = sum w^2 - 2*eps*sum w reduced
// in-register via quarter-group shuffles. Epilogue: scores + softmax + loss,
// final mean via last-block-done reduction (deterministic fixed-order sum).
__global__ __launch_bounds__(512) void proto_one_kernel(
    const float* __restrict__ x,
    const int*   __restrict__ label,
    const float* __restrict__ w,
    float* __restrict__ scores,
    float* __restrict__ loss_out,
    float* __restrict__ row_loss,
    unsigned int* __restrict__ cnt)
{
    const int tid  = threadIdx.x;
    const int wave = tid >> 6;
    const int lane = tid & 63;
    const int l15  = lane & 15;
    const int q    = lane >> 4;
    const int n0   = blockIdx.x * 16;

    __shared__ float sxs[16];
    __shared__ float wm[8][16];
    __shared__ float we[8][16];
    __shared__ float gm[16];
    __shared__ float slab[16];
    __shared__ float rl[16];
    __shared__ float red[8];
    __shared__ unsigned int isLast;

    // ---- sx[row] = sum_d (x+eps)^2 : threads 0..255 ----
    if (tid < 256) {
        const int row   = tid >> 4;
        const int chunk = tid & 15;
        const float4 a = *(const float4*)&x[(size_t)(n0 + row) * D_DIM + chunk * 8];
        const float4 b = *(const float4*)&x[(size_t)(n0 + row) * D_DIM + chunk * 8 + 4];
        float p = 0.f;
        p = fmaf(a.x + EPS, a.x + EPS, p);
        p = fmaf(a.y + EPS, a.y + EPS, p);
        p = fmaf(a.z + EPS, a.z + EPS, p);
        p = fmaf(a.w + EPS, a.w + EPS, p);
        p = fmaf(b.x + EPS, b.x + EPS, p);
        p = fmaf(b.y + EPS, b.y + EPS, p);
        p = fmaf(b.z + EPS, b.z + EPS, p);
        p = fmaf(b.w + EPS, b.w + EPS, p);
        p += __shfl_xor(p, 1);
        p += __shfl_xor(p, 2);
        p += __shfl_xor(p, 4);
        p += __shfl_xor(p, 8);
        if (chunk == 0) sxs[row] = p;
    }

    // ---- A fragments: lane l -> row (l&15), k = q*8 + j within each 32-step ----
    short8v afrag[4];
#pragma unroll
    for (int t = 0; t < 4; ++t) {
        const int row = n0 + l15;
        const int d0  = t * 32 + q * 8;
        const float4 a = *(const float4*)&x[(size_t)row * D_DIM + d0];
        const float4 b = *(const float4*)&x[(size_t)row * D_DIM + d0 + 4];
        short8v f;
        f[0] = (short)f2bf(a.x); f[1] = (short)f2bf(a.y);
        f[2] = (short)f2bf(a.z); f[3] = (short)f2bf(a.w);
        f[4] = (short)f2bf(b.x); f[5] = (short)f2bf(b.y);
        f[6] = (short)f2bf(b.z); f[7] = (short)f2bf(b.w);
        afrag[t] = f;
    }

    // ---- B fragments direct from global + c[k] in-register + MFMA ----
    f32x4 acc[4];
    float ck[4];
    const int colbase = wave * 64;
#pragma unroll
    for (int c = 0; c < 4; ++c) {
        acc[c] = (f32x4){0.f, 0.f, 0.f, 0.f};
        float s1 = 0.f, s2 = 0.f;
        const int col = colbase + c * 16 + l15;
#pragma unroll
        for (int t = 0; t < 4; ++t) {
            short8v bf;
#pragma unroll
            for (int j = 0; j < 8; ++j) {
                const float v = w[(size_t)(t * 32 + q * 8 + j) * K_CLS + col];
                s1 += v;
                s2 = fmaf(v, v, s2);
                bf[j] = (short)f2bf(v);
            }
            acc[c] = __builtin_amdgcn_mfma_f32_16x16x32_bf16(afrag[t], bf, acc[c], 0, 0, 0);
        }
        // lanes l, l^16, l^32, l^48 hold the same col, disjoint d-ranges
        s1 += __shfl_xor(s1, 16); s1 += __shfl_xor(s1, 32);
        s2 += __shfl_xor(s2, 16); s2 += __shfl_xor(s2, 32);
        ck[c] = s2 - 2.f * EPS * s1;
    }

    __syncthreads();   // sxs ready

    // ---- scores from registers (C/D: col = lane&15, row = q*4 + reg) ----
    float sv[4][4];
#pragma unroll
    for (int c = 0; c < 4; ++c) {
        const int col = colbase + c * 16 + l15;
#pragma unroll
        for (int j = 0; j < 4; ++j) {
            const int row = q * 4 + j;
            const float dist = sxs[row] + ck[c] - 2.f * acc[c][j];
            sv[c][j] = -sqrtf(dist);
            scores[(size_t)(n0 + row) * K_CLS + col] = sv[c][j];
        }
    }

    // ---- per-row max: in-register over c, shuffle over 16-lane col group ----
#pragma unroll
    for (int j = 0; j < 4; ++j) {
        float m = fmaxf(fmaxf(sv[0][j], sv[1][j]), fmaxf(sv[2][j], sv[3][j]));
        m = fmaxf(m, __shfl_xor(m, 1));
        m = fmaxf(m, __shfl_xor(m, 2));
        m = fmaxf(m, __shfl_xor(m, 4));
        m = fmaxf(m, __shfl_xor(m, 8));
        if (l15 == 0) wm[wave][q * 4 + j] = m;
    }
    __syncthreads();
    if (tid < 16) {
        float g = wm[0][tid];
#pragma unroll
        for (int ww = 1; ww < 8; ++ww) g = fmaxf(g, wm[ww][tid]);
        gm[tid] = g;
    }
    __syncthreads();

    // ---- expsum + label-score pick ----
#pragma unroll
    for (int j = 0; j < 4; ++j) {
        const int row = q * 4 + j;
        const float m = gm[row];
        const int lab = label[n0 + row];
        float e = 0.f;
#pragma unroll
        for (int c = 0; c < 4; ++c) {
            e += expf(sv[c][j] - m);
            if (colbase + c * 16 + l15 == lab) slab[row] = sv[c][j];
        }
        e += __shfl_xor(e, 1);
        e += __shfl_xor(e, 2);
        e += __shfl_xor(e, 4);
        e += __shfl_xor(e, 8);
        if (l15 == 0) we[wave][row] = e;
    }
    __syncthreads();
    if (tid < 16) {
        float es = we[0][tid];
#pragma unroll
        for (int ww = 1; ww < 8; ++ww) es += we[ww][tid];
        rl[tid] = -(slab[tid] - gm[tid] - logf(es));
    }
    __syncthreads();

    // ---- publish row losses, last block reduces the mean ----
    if (tid == 0) {
        float4* dst = (float4*)&row_loss[n0];
        const float4* src = (const float4*)&rl[0];
        dst[0] = src[0]; dst[1] = src[1]; dst[2] = src[2]; dst[3] = src[3];
        __threadfence();
        const unsigned int old = atomicAdd(cnt, 1u);
        isLast = (old == NBLK - 1) ? 1u : 0u;
    }
    __syncthreads();

    if (isLast) {
        __threadfence();
        float s = 0.f;
        for (int i = tid; i < N_ROWS; i += 512) s += row_loss[i];
        s += __shfl_xor(s, 1);
        s += __shfl_xor(s, 2);
        s += __shfl_xor(s, 4);
        s += __shfl_xor(s, 8);
        s += __shfl_xor(s, 16);
        s += __shfl_xor(s, 32);
        if (lane == 0) red[wave] = s;
        __syncthreads();
        if (tid == 0) {
            float tot = 0.f;
#pragma unroll
            for (int ww = 0; ww < 8; ++ww) tot += red[ww];
            loss_out[0] = tot * (1.0f / N_ROWS);
        }
    }
}

extern "C" void kernel_launch(void* const* d_in, const int* in_sizes, int n_in,
                              void* d_out, int out_size, void* d_ws, size_t ws_size,
                              hipStream_t stream)
{
    const float* x     = (const float*)d_in[0];
    const int*   label = (const int*)d_in[1];
    const float* w     = (const float*)d_in[2];

    float* scores   = (float*)d_out;                           // N*K floats
    float* loss_out = (float*)d_out + (size_t)N_ROWS * K_CLS;  // 1 float
    float* row_loss = (float*)d_ws;                            // 4096 floats
    unsigned int* cnt = (unsigned int*)((char*)d_ws + 16384);  // 1 uint

    hipMemsetAsync(cnt, 0, 4, stream);
    proto_one_kernel<<<NBLK, 512, 0, stream>>>(x, label, w, scores, loss_out,
                                               row_loss, cnt);
}

// Round 6
// 22.831 us; speedup vs baseline: 1.3969x; 1.3969x over previous
//
#include <hip/hip_runtime.h>
#include <math.h>

#define N_ROWS 4096
#define D_DIM  128
#define K_CLS  512
#define EPS    1e-6f
#define NBLK   (N_ROWS / 16)   // 256 blocks, one per CU

typedef __attribute__((ext_vector_type(8))) short short8v;
typedef __attribute__((ext_vector_type(4))) float f32x4;

__device__ __forceinline__ unsigned short f2bf(float f) {
    unsigned int u = __float_as_uint(f);
    u += 0x7FFF + ((u >> 16) & 1);   // round-to-nearest-even
    return (unsigned short)(u >> 16);
}

// Fused kernel: block = 16 rows x 512 cols, 512 threads (8 waves).
// Wave w owns cols 64w..64w+63. B-fragments loaded straight from global w
// (L2-hot) with on-the-fly bf16 convert; c[k] = sum w^2 - 2*eps*sum w reduced
// in-register via quarter-group shuffles. Epilogue: scores + register softmax
// + per-row loss -> row_loss. (Loss mean done by a second tiny kernel; no
// atomics, no memset dispatch.)
__global__ __launch_bounds__(512) void proto_main_kernel(
    const float* __restrict__ x,
    const int*   __restrict__ label,
    const float* __restrict__ w,
    float* __restrict__ scores,
    float* __restrict__ row_loss)
{
    const int tid  = threadIdx.x;
    const int wave = tid >> 6;
    const int lane = tid & 63;
    const int l15  = lane & 15;
    const int q    = lane >> 4;
    const int n0   = blockIdx.x * 16;

    __shared__ float sxs[16];
    __shared__ float wm[8][16];
    __shared__ float we[8][16];
    __shared__ float gm[16];
    __shared__ float slab[16];

    // ---- sx[row] = sum_d (x+eps)^2 : threads 0..255 ----
    if (tid < 256) {
        const int row   = tid >> 4;
        const int chunk = tid & 15;
        const float4 a = *(const float4*)&x[(size_t)(n0 + row) * D_DIM + chunk * 8];
        const float4 b = *(const float4*)&x[(size_t)(n0 + row) * D_DIM + chunk * 8 + 4];
        float p = 0.f;
        p = fmaf(a.x + EPS, a.x + EPS, p);
        p = fmaf(a.y + EPS, a.y + EPS, p);
        p = fmaf(a.z + EPS, a.z + EPS, p);
        p = fmaf(a.w + EPS, a.w + EPS, p);
        p = fmaf(b.x + EPS, b.x + EPS, p);
        p = fmaf(b.y + EPS, b.y + EPS, p);
        p = fmaf(b.z + EPS, b.z + EPS, p);
        p = fmaf(b.w + EPS, b.w + EPS, p);
        p += __shfl_xor(p, 1);
        p += __shfl_xor(p, 2);
        p += __shfl_xor(p, 4);
        p += __shfl_xor(p, 8);
        if (chunk == 0) sxs[row] = p;
    }

    // ---- A fragments: lane l -> row (l&15), k = q*8 + j within each 32-step ----
    short8v afrag[4];
#pragma unroll
    for (int t = 0; t < 4; ++t) {
        const int row = n0 + l15;
        const int d0  = t * 32 + q * 8;
        const float4 a = *(const float4*)&x[(size_t)row * D_DIM + d0];
        const float4 b = *(const float4*)&x[(size_t)row * D_DIM + d0 + 4];
        short8v f;
        f[0] = (short)f2bf(a.x); f[1] = (short)f2bf(a.y);
        f[2] = (short)f2bf(a.z); f[3] = (short)f2bf(a.w);
        f[4] = (short)f2bf(b.x); f[5] = (short)f2bf(b.y);
        f[6] = (short)f2bf(b.z); f[7] = (short)f2bf(b.w);
        afrag[t] = f;
    }

    // ---- B fragments direct from global + c[k] in-register + MFMA ----
    f32x4 acc[4];
    float ck[4];
    const int colbase = wave * 64;
#pragma unroll
    for (int c = 0; c < 4; ++c) {
        acc[c] = (f32x4){0.f, 0.f, 0.f, 0.f};
        float s1 = 0.f, s2 = 0.f;
        const int col = colbase + c * 16 + l15;
#pragma unroll
        for (int t = 0; t < 4; ++t) {
            short8v bf;
#pragma unroll
            for (int j = 0; j < 8; ++j) {
                const float v = w[(size_t)(t * 32 + q * 8 + j) * K_CLS + col];
                s1 += v;
                s2 = fmaf(v, v, s2);
                bf[j] = (short)f2bf(v);
            }
            acc[c] = __builtin_amdgcn_mfma_f32_16x16x32_bf16(afrag[t], bf, acc[c], 0, 0, 0);
        }
        // lanes l, l^16, l^32, l^48 hold the same col, disjoint d-ranges
        s1 += __shfl_xor(s1, 16); s1 += __shfl_xor(s1, 32);
        s2 += __shfl_xor(s2, 16); s2 += __shfl_xor(s2, 32);
        ck[c] = s2 - 2.f * EPS * s1;
    }

    __syncthreads();   // sxs ready

    // ---- scores from registers (C/D: col = lane&15, row = q*4 + reg) ----
    float sv[4][4];
#pragma unroll
    for (int c = 0; c < 4; ++c) {
        const int col = colbase + c * 16 + l15;
#pragma unroll
        for (int j = 0; j < 4; ++j) {
            const int row = q * 4 + j;
            const float dist = sxs[row] + ck[c] - 2.f * acc[c][j];
            sv[c][j] = -sqrtf(dist);
            scores[(size_t)(n0 + row) * K_CLS + col] = sv[c][j];
        }
    }

    // ---- per-row max: in-register over c, shuffle over 16-lane col group ----
#pragma unroll
    for (int j = 0; j < 4; ++j) {
        float m = fmaxf(fmaxf(sv[0][j], sv[1][j]), fmaxf(sv[2][j], sv[3][j]));
        m = fmaxf(m, __shfl_xor(m, 1));
        m = fmaxf(m, __shfl_xor(m, 2));
        m = fmaxf(m, __shfl_xor(m, 4));
        m = fmaxf(m, __shfl_xor(m, 8));
        if (l15 == 0) wm[wave][q * 4 + j] = m;
    }
    __syncthreads();
    if (tid < 16) {
        float g = wm[0][tid];
#pragma unroll
        for (int ww = 1; ww < 8; ++ww) g = fmaxf(g, wm[ww][tid]);
        gm[tid] = g;
    }
    __syncthreads();

    // ---- expsum + label-score pick ----
#pragma unroll
    for (int j = 0; j < 4; ++j) {
        const int row = q * 4 + j;
        const float m = gm[row];
        const int lab = label[n0 + row];
        float e = 0.f;
#pragma unroll
        for (int c = 0; c < 4; ++c) {
            e += expf(sv[c][j] - m);
            if (colbase + c * 16 + l15 == lab) slab[row] = sv[c][j];
        }
        e += __shfl_xor(e, 1);
        e += __shfl_xor(e, 2);
        e += __shfl_xor(e, 4);
        e += __shfl_xor(e, 8);
        if (l15 == 0) we[wave][row] = e;
    }
    __syncthreads();
    if (tid < 16) {
        float es = we[0][tid];
#pragma unroll
        for (int ww = 1; ww < 8; ++ww) es += we[ww][tid];
        row_loss[n0 + tid] = -(slab[tid] - gm[tid] - logf(es));
    }
}

// Deterministic single-block reduction of per-row losses -> mean.
__global__ __launch_bounds__(256) void loss_reduce_kernel(
    const float* __restrict__ row_loss, float* __restrict__ out)
{
    __shared__ float red[4];
    const int tid = threadIdx.x;
    float sum = 0.f;
    for (int i = tid; i < N_ROWS; i += 256) sum += row_loss[i];
#pragma unroll
    for (int off = 32; off >= 1; off >>= 1) sum += __shfl_xor(sum, off);
    if ((tid & 63) == 0) red[tid >> 6] = sum;
    __syncthreads();
    if (tid == 0)
        out[0] = (red[0] + red[1] + red[2] + red[3]) * (1.0f / N_ROWS);
}

extern "C" void kernel_launch(void* const* d_in, const int* in_sizes, int n_in,
                              void* d_out, int out_size, void* d_ws, size_t ws_size,
                              hipStream_t stream)
{
    const float* x     = (const float*)d_in[0];
    const int*   label = (const int*)d_in[1];
    const float* w     = (const float*)d_in[2];

    float* scores   = (float*)d_out;                           // N*K floats
    float* loss_out = (float*)d_out + (size_t)N_ROWS * K_CLS;  // 1 float
    float* row_loss = (float*)d_ws;                            // 4096 floats

    proto_main_kernel<<<NBLK, 512, 0, stream>>>(x, label, w, scores, row_loss);
    loss_reduce_kernel<<<1, 256, 0, stream>>>(row_loss, loss_out);
}